// Round 10
// baseline (1609.321 us; speedup 1.0000x reference)
//
#include <hip/hip_runtime.h>
#include <hip/hip_bf16.h>
#include <math.h>

#define WW 192
#define NTOT 256
#define HNN 128
#define CC 128
#define NH 4
#define NLAY 4
#define EPSF 1e-5f
#define SCALE 0.17677669529663687f

typedef __attribute__((ext_vector_type(8))) short short8_t;
typedef __attribute__((ext_vector_type(4))) float f32x4;

#define MFMA(a, b, c) __builtin_amdgcn_mfma_f32_16x16x32_bf16(a, b, c, 0, 0, 0)

__device__ __forceinline__ ushort f2b(float f) {
  union { float f; uint u; } x; x.f = f;
  uint r = x.u + 0x7fffu + ((x.u >> 16) & 1u);
  return (ushort)(r >> 16);
}

// ---------------------------------------------------------------------------
// Build feat (W, 256, 128) f32 from feat_left/right (2, 128, 64, 192).
// ---------------------------------------------------------------------------
__global__ __launch_bounds__(256) void k_build_feat(const float* __restrict__ L,
                                                    const float* __restrict__ R,
                                                    float* __restrict__ feat) {
  __shared__ float tile[32][33];
  int wt = blockIdx.x, h0 = blockIdx.y, z = blockIdx.z;
  int ct = z & 3, b = (z >> 2) & 1, side = z >> 3;
  const float* src = side ? R : L;
  int tx = threadIdx.x & 31, ty = threadIdx.x >> 5;
  const float* sp = src + ((size_t)(b * 128 + ct * 32) * 64 + h0) * 192 + wt * 32;
  #pragma unroll
  for (int yy = 0; yy < 4; ++yy) {
    int c = ty * 4 + yy;
    tile[c][tx] = sp[(size_t)c * 64 * 192 + tx];
  }
  __syncthreads();
  int n = 2 * h0 + b + side * 128;
  #pragma unroll
  for (int yy = 0; yy < 4; ++yy) {
    int w = ty * 4 + yy;
    feat[((size_t)(wt * 32 + w) * 256 + n) * 128 + ct * 32 + tx] = tile[tx][w];
  }
}

// ---------------------------------------------------------------------------
// One-shot weight conversion f32 -> bf16.
// ---------------------------------------------------------------------------
__global__ __launch_bounds__(256) void k_wconv(
    const float* __restrict__ s_iw, const float* __restrict__ s_ow,
    const float* __restrict__ c_iw, const float* __restrict__ c_ow,
    ushort* __restrict__ out) {
  int i4 = (blockIdx.x * 256 + threadIdx.x) * 4;
  const float* src;
  int off;
  if (i4 < 196608) { src = s_iw; off = i4; }
  else if (i4 < 262144) { src = s_ow; off = i4 - 196608; }
  else if (i4 < 458752) { src = c_iw; off = i4 - 262144; }
  else { src = c_ow; off = i4 - 458752; }
  float4 v = *(const float4*)(src + off);
  ushort4 o;
  o.x = f2b(v.x); o.y = f2b(v.y); o.z = f2b(v.z); o.w = f2b(v.w);
  *(ushort4*)(out + i4) = o;
}

// ---------------------------------------------------------------------------
// LayerNorm over C=128, f32 in -> bf16 out (used once for layer-0 input).
// ---------------------------------------------------------------------------
__global__ __launch_bounds__(256) void k_ln(const float* __restrict__ src,
                                            ushort* __restrict__ dst,
                                            const float* __restrict__ g,
                                            const float* __restrict__ b,
                                            int n0, int nsub) {
  int t = blockIdx.x * 4 + (threadIdx.x >> 6);
  int lane = threadIdx.x & 63;
  int w = t / nsub, h = t - w * nsub;
  size_t row = (size_t)(w * NTOT + n0 + h) * CC;
  int c0 = lane * 2;
  float2 x = *(const float2*)(src + row + c0);
  float s = x.x + x.y;
  float s2 = x.x * x.x + x.y * x.y;
  #pragma unroll
  for (int o = 1; o < 64; o <<= 1) {
    s += __shfl_xor(s, o);
    s2 += __shfl_xor(s2, o);
  }
  float m = s * (1.0f / 128.0f);
  float var = s2 * (1.0f / 128.0f) - m * m;
  float inv = rsqrtf(var + EPSF);
  float oa = (x.x - m) * inv * g[c0] + b[c0];
  float ob = (x.y - m) * inv * g[c0 + 1] + b[c0 + 1];
  uint pack = (uint)f2b(oa) | ((uint)f2b(ob) << 16);
  *(uint*)(dst + row + c0) = pack;
}

// ---------------------------------------------------------------------------
// Pure-bf16 MFMA GEMM (projections): Y = X @ Wb^T + bias, bf16 out.
// ---------------------------------------------------------------------------
__global__ __launch_bounds__(256) void k_gemm_bf16(
    const ushort* __restrict__ X, int xN, int x0,
    const ushort* __restrict__ Wb, const float* __restrict__ bias,
    ushort* __restrict__ Y, int yN, int y0, int ystride,
    int T, int nsub) {
  extern __shared__ char smem[];
  ushort* As = (ushort*)smem;
  ushort* Bs = As + 128 * 128;
  float* biasS = (float*)(Bs + 128 * 128);

  int bm = blockIdx.x, bn = blockIdx.y;
  int tid = threadIdx.x;

  {
    int row = tid >> 1;
    int ce0 = (tid & 1) * 64;
    int t = bm * 128 + row;
    int w = t / nsub, h = t - w * nsub;
    const ushort* src = X + (size_t)(w * xN + x0 + h) * CC + ce0;
    #pragma unroll
    for (int i = 0; i < 8; ++i) {
      short8_t v = *(const short8_t*)(src + i * 8);
      int cb = (ce0 + i * 8) * 2;
      *(short8_t*)((char*)As + row * 256 + (cb ^ ((row & 7) << 4))) = v;
    }
    const ushort* wsrc = Wb + (size_t)(bn * 128 + row) * CC + ce0;
    #pragma unroll
    for (int i = 0; i < 8; ++i) {
      short8_t v = *(const short8_t*)(wsrc + i * 8);
      int cb = (ce0 + i * 8) * 2;
      *(short8_t*)((char*)Bs + row * 256 + (cb ^ ((row & 7) << 4))) = v;
    }
    if (tid < 128) biasS[tid] = bias[bn * 128 + tid];
  }
  __syncthreads();

  int lane = tid & 63, wid = tid >> 6;
  int wm = (wid >> 1) * 64, wn = (wid & 1) * 64;
  int r = lane & 15, g = lane >> 4;

  f32x4 acc[4][4] = {};
  #pragma unroll
  for (int kc = 0; kc < 4; ++kc) {
    short8_t af[4], bf[4];
    #pragma unroll
    for (int mt = 0; mt < 4; ++mt) {
      int row = wm + mt * 16 + r;
      af[mt] = *(const short8_t*)((const char*)As + row * 256 + ((kc * 64 + g * 16) ^ ((row & 7) << 4)));
    }
    #pragma unroll
    for (int nt = 0; nt < 4; ++nt) {
      int row = wn + nt * 16 + r;
      bf[nt] = *(const short8_t*)((const char*)Bs + row * 256 + ((kc * 64 + g * 16) ^ ((row & 7) << 4)));
    }
    __builtin_amdgcn_s_setprio(1);
    #pragma unroll
    for (int mt = 0; mt < 4; ++mt)
      #pragma unroll
      for (int nt = 0; nt < 4; ++nt)
        acc[mt][nt] = MFMA(af[mt], bf[nt], acc[mt][nt]);
    __builtin_amdgcn_s_setprio(0);
  }

  #pragma unroll
  for (int mt = 0; mt < 4; ++mt) {
    #pragma unroll
    for (int reg = 0; reg < 4; ++reg) {
      int t = bm * 128 + wm + mt * 16 + g * 4 + reg;
      int w = t / nsub, h = t - w * nsub;
      size_t ybase = (size_t)(w * yN + y0 + h) * ystride + bn * 128;
      #pragma unroll
      for (int nt = 0; nt < 4; ++nt) {
        int nn = wn + nt * 16 + r;
        Y[ybase + nn] = f2b(acc[mt][nt][reg] + biasS[nn]);
      }
    }
  }
}

// ---------------------------------------------------------------------------
// Out-projection GEMM (N=128, bn=0) + f32 residual + up to TWO fused
// LayerNorms of the updated rows (row stats block-local: shfl + 2KB LDS).
// dstX layout: (w*dXN + dXn0 + h)*CC.
// ---------------------------------------------------------------------------
__global__ __launch_bounds__(256) void k_gemm_out(
    const ushort* __restrict__ X, int xN,
    const ushort* __restrict__ Wb, const float* __restrict__ bias,
    float* __restrict__ Y, int y0, float* __restrict__ Ymir,
    const float* __restrict__ g1, const float* __restrict__ b1,
    ushort* __restrict__ dst1, int d1N, int d1n0,
    const float* __restrict__ g2, const float* __restrict__ b2,
    ushort* __restrict__ dst2, int d2N, int d2n0,
    int T, int nsub) {
  extern __shared__ char smem[];
  ushort* As = (ushort*)smem;                 // 32768
  ushort* Bs = As + 128 * 128;                // 32768
  float* biasS = (float*)(Bs + 128 * 128);    // 512
  float* rsum = biasS + 128;                  // 1024 (128 x 2)
  float* rsq  = rsum + 256;                   // 1024

  int bm = blockIdx.x;
  int tid = threadIdx.x;

  {
    int row = tid >> 1;
    int ce0 = (tid & 1) * 64;
    int t = bm * 128 + row;
    int w = t / nsub, h = t - w * nsub;
    const ushort* src = X + (size_t)(w * xN + h) * CC + ce0;
    #pragma unroll
    for (int i = 0; i < 8; ++i) {
      short8_t v = *(const short8_t*)(src + i * 8);
      int cb = (ce0 + i * 8) * 2;
      *(short8_t*)((char*)As + row * 256 + (cb ^ ((row & 7) << 4))) = v;
    }
    const ushort* wsrc = Wb + (size_t)row * CC + ce0;
    #pragma unroll
    for (int i = 0; i < 8; ++i) {
      short8_t v = *(const short8_t*)(wsrc + i * 8);
      int cb = (ce0 + i * 8) * 2;
      *(short8_t*)((char*)Bs + row * 256 + (cb ^ ((row & 7) << 4))) = v;
    }
    if (tid < 128) biasS[tid] = bias[tid];
  }
  __syncthreads();

  int lane = tid & 63, wid = tid >> 6;
  int wm = (wid >> 1) * 64, wn = (wid & 1) * 64;
  int r = lane & 15, g = lane >> 4;
  int g4 = g * 4;

  f32x4 acc[4][4] = {};
  #pragma unroll
  for (int kc = 0; kc < 4; ++kc) {
    short8_t af[4], bf[4];
    #pragma unroll
    for (int mt = 0; mt < 4; ++mt) {
      int row = wm + mt * 16 + r;
      af[mt] = *(const short8_t*)((const char*)As + row * 256 + ((kc * 64 + g * 16) ^ ((row & 7) << 4)));
    }
    #pragma unroll
    for (int nt = 0; nt < 4; ++nt) {
      int row = wn + nt * 16 + r;
      bf[nt] = *(const short8_t*)((const char*)Bs + row * 256 + ((kc * 64 + g * 16) ^ ((row & 7) << 4)));
    }
    __builtin_amdgcn_s_setprio(1);
    #pragma unroll
    for (int mt = 0; mt < 4; ++mt)
      #pragma unroll
      for (int nt = 0; nt < 4; ++nt)
        acc[mt][nt] = MFMA(af[mt], bf[nt], acc[mt][nt]);
    __builtin_amdgcn_s_setprio(0);
  }

  // ---- residual + row stats ----
  float nvv[4][4][4];
  #pragma unroll
  for (int mt = 0; mt < 4; ++mt) {
    #pragma unroll
    for (int reg = 0; reg < 4; ++reg) {
      int rloc = wm + mt * 16 + g4 + reg;
      int t = bm * 128 + rloc;
      int w = t / nsub, h = t - w * nsub;
      size_t ybase = (size_t)(w * NTOT + y0 + h) * CC;
      float s = 0.f, q = 0.f;
      #pragma unroll
      for (int nt = 0; nt < 4; ++nt) {
        int nn = wn + nt * 16 + r;
        float nv = Y[ybase + nn] + acc[mt][nt][reg] + biasS[nn];
        Y[ybase + nn] = nv;
        if (Ymir) Ymir[ybase + nn] = nv;
        nvv[mt][reg][nt] = nv;
        s += nv;
        q += nv * nv;
      }
      #pragma unroll
      for (int o = 1; o < 16; o <<= 1) {
        s += __shfl_xor(s, o);
        q += __shfl_xor(q, o);
      }
      if (r == 0) {
        rsum[rloc * 2 + (wn >> 6)] = s;
        rsq[rloc * 2 + (wn >> 6)] = q;
      }
    }
  }
  if (!dst1) return;
  __syncthreads();

  float g1c[4], b1c[4], g2c[4], b2c[4];
  #pragma unroll
  for (int nt = 0; nt < 4; ++nt) {
    int nn = wn + nt * 16 + r;
    g1c[nt] = g1[nn]; b1c[nt] = b1[nn];
    if (dst2) { g2c[nt] = g2[nn]; b2c[nt] = b2[nn]; }
  }
  #pragma unroll
  for (int mt = 0; mt < 4; ++mt) {
    #pragma unroll
    for (int reg = 0; reg < 4; ++reg) {
      int rloc = wm + mt * 16 + g4 + reg;
      int t = bm * 128 + rloc;
      int w = t / nsub, h = t - w * nsub;
      float S = rsum[rloc * 2] + rsum[rloc * 2 + 1];
      float Q = rsq[rloc * 2] + rsq[rloc * 2 + 1];
      float m = S * (1.0f / 128.0f);
      float inv = rsqrtf(Q * (1.0f / 128.0f) - m * m + EPSF);
      size_t d1base = (size_t)(w * d1N + d1n0 + h) * CC;
      size_t d2base = dst2 ? (size_t)(w * d2N + d2n0 + h) * CC : 0;
      #pragma unroll
      for (int nt = 0; nt < 4; ++nt) {
        int nn = wn + nt * 16 + r;
        float xn = (nvv[mt][reg][nt] - m) * inv;
        dst1[d1base + nn] = f2b(xn * g1c[nt] + b1c[nt]);
        if (dst2) dst2[d2base + nn] = f2b(xn * g2c[nt] + b2c[nt]);
      }
    }
  }
}

// ---------------------------------------------------------------------------
// Batched rr GEMM (once): out_all[z] = pos_enc @ W_z[:256].T + b_z[:256]
// ---------------------------------------------------------------------------
__global__ __launch_bounds__(256) void k_rr(
    const float* __restrict__ pos_enc,
    const float* __restrict__ s_iw, const float* __restrict__ s_ib,
    const float* __restrict__ c_iw, const float* __restrict__ c_ib,
    ushort* __restrict__ out_all) {
  extern __shared__ char smem[];
  ushort* As = (ushort*)smem;
  ushort* Bs = As + 128 * 128;
  float* biasS = (float*)(Bs + 128 * 128);

  int bm = blockIdx.x, bn = blockIdx.y, z = blockIdx.z;
  int layer = z >> 1;
  const float* Wt = ((z & 1) ? c_iw : s_iw) + (size_t)layer * 384 * CC;
  const float* bias = ((z & 1) ? c_ib : s_ib) + layer * 384;
  ushort* out = out_all + (size_t)z * 383 * 256;
  int tid = threadIdx.x;

  {
    int row = tid >> 1;
    int ce0 = (tid & 1) * 64;
    int t = bm * 128 + row;
    bool ok = (t < 383);
    const float* src = pos_enc + (size_t)t * CC + ce0;
    #pragma unroll
    for (int i = 0; i < 8; ++i) {
      float4 v0 = ok ? *(const float4*)(src + i * 8) : make_float4(0.f, 0.f, 0.f, 0.f);
      float4 v1 = ok ? *(const float4*)(src + i * 8 + 4) : make_float4(0.f, 0.f, 0.f, 0.f);
      short8_t pv;
      pv[0] = (short)f2b(v0.x); pv[1] = (short)f2b(v0.y);
      pv[2] = (short)f2b(v0.z); pv[3] = (short)f2b(v0.w);
      pv[4] = (short)f2b(v1.x); pv[5] = (short)f2b(v1.y);
      pv[6] = (short)f2b(v1.z); pv[7] = (short)f2b(v1.w);
      int cb = (ce0 + i * 8) * 2;
      *(short8_t*)((char*)As + row * 256 + (cb ^ ((row & 7) << 4))) = pv;
    }
    const float* wsrc = Wt + (size_t)(bn * 128 + row) * CC + ce0;
    #pragma unroll
    for (int i = 0; i < 8; ++i) {
      float4 v0 = *(const float4*)(wsrc + i * 8);
      float4 v1 = *(const float4*)(wsrc + i * 8 + 4);
      short8_t pv;
      pv[0] = (short)f2b(v0.x); pv[1] = (short)f2b(v0.y);
      pv[2] = (short)f2b(v0.z); pv[3] = (short)f2b(v0.w);
      pv[4] = (short)f2b(v1.x); pv[5] = (short)f2b(v1.y);
      pv[6] = (short)f2b(v1.z); pv[7] = (short)f2b(v1.w);
      int cb = (ce0 + i * 8) * 2;
      *(short8_t*)((char*)Bs + row * 256 + (cb ^ ((row & 7) << 4))) = pv;
    }
    if (tid < 128) biasS[tid] = bias[bn * 128 + tid];
  }
  __syncthreads();

  int lane = tid & 63, wid = tid >> 6;
  int wm = (wid >> 1) * 64, wn = (wid & 1) * 64;
  int r = lane & 15, g = lane >> 4;

  f32x4 acc[4][4] = {};
  #pragma unroll
  for (int kc = 0; kc < 4; ++kc) {
    short8_t af[4], bf[4];
    #pragma unroll
    for (int mt = 0; mt < 4; ++mt) {
      int row = wm + mt * 16 + r;
      af[mt] = *(const short8_t*)((const char*)As + row * 256 + ((kc * 64 + g * 16) ^ ((row & 7) << 4)));
    }
    #pragma unroll
    for (int nt = 0; nt < 4; ++nt) {
      int row = wn + nt * 16 + r;
      bf[nt] = *(const short8_t*)((const char*)Bs + row * 256 + ((kc * 64 + g * 16) ^ ((row & 7) << 4)));
    }
    #pragma unroll
    for (int mt = 0; mt < 4; ++mt)
      #pragma unroll
      for (int nt = 0; nt < 4; ++nt)
        acc[mt][nt] = MFMA(af[mt], bf[nt], acc[mt][nt]);
  }

  #pragma unroll
  for (int mt = 0; mt < 4; ++mt) {
    #pragma unroll
    for (int reg = 0; reg < 4; ++reg) {
      int t = bm * 128 + wm + mt * 16 + g * 4 + reg;
      if (t < 383) {
        #pragma unroll
        for (int nt = 0; nt < 4; ++nt) {
          int nn = wn + nt * 16 + r;
          out[(size_t)t * 256 + bn * 128 + nn] = f2b(acc[mt][nt][reg] + biasS[nn]);
        }
      }
    }
  }
}

// ---------------------------------------------------------------------------
// Fused rel-pos attention (round-8 body) with NGRP n-values per block
// (rr-table L1 reuse). Grid = (nblk/NGRP)*NH*3.
// ---------------------------------------------------------------------------
#define KS_ST 36
#define VT_ST 196
#define B2_ST 37
#define PL_ST 20

template <int SGN, int NGRP>
__global__ __launch_bounds__(256, 4) void k_attn_mfma(
    const ushort* __restrict__ qbuf, int qstride, int qoff, int qN, int qn0,
    const ushort* __restrict__ kvbuf, int kvstride, int koff, int voff, int kN, int kn0,
    const ushort* __restrict__ rrb,
    ushort* __restrict__ obuf, int oN,
    int nblk) {
  __shared__ ushort Ks[192 * KS_ST];
  __shared__ ushort Vt[32 * VT_ST];
  __shared__ float Sb[4 * 16 * B2_ST];
  __shared__ uint PLb[4 * 16 * PL_ST];

  int bid = blockIdx.x;
  int nb2 = nblk / NGRP;
  int n0 = (bid % nb2) * NGRP;
  int rest = bid / nb2;
  int h = rest & 3;
  int ts = rest >> 2;
  int tid = threadIdx.x;
  int lane = tid & 63, wid = tid >> 6;
  int r = lane & 15, g = lane >> 4;
  int g4 = g * 4;

  float* flat = Sb + wid * 16 * B2_ST;
  uint* PL = PLb + wid * 16 * PL_ST;
  const ushort* KRg = rrb + 128 + h * 32 + g * 8;
  const ushort* QRg = rrb + h * 32 + g * 8;
  const f32x4 zf = {0.f, 0.f, 0.f, 0.f};

  int ca = (SGN < 0) ? (r + 1) : (31 - r);
  int cbn = (SGN < 0) ? (17 + r) : (15 - r);
  int rdcol = 16 - r + g4;
  int w0 = (ts * 4 + wid) * 16;

  for (int ni = 0; ni < NGRP; ++ni) {
    int n = n0 + ni;
    if (ni) __syncthreads();
    for (int i = tid; i < 768; i += 256) {
      int row = i >> 2, c8 = (i & 3) * 8;
      *(short8_t*)&Ks[row * KS_ST + c8] =
          *(const short8_t*)(kvbuf + (size_t)(row * kN + kn0 + n) * kvstride + koff + h * 32 + c8);
    }
    {
      uint* Vtu = (uint*)Vt;
      for (int i = tid; i < 384; i += 256) {
        int dg = i / 96;
        int p = i - dg * 96;
        const ushort* vb = kvbuf + (size_t)((2 * p) * kN + kn0 + n) * kvstride + voff + h * 32 + dg * 8;
        short8_t a = *(const short8_t*)vb;
        short8_t b = *(const short8_t*)(vb + (size_t)kN * kvstride);
        #pragma unroll
        for (int j = 0; j < 8; ++j)
          Vtu[(dg * 8 + j) * 98 + p] = ((uint)(ushort)a[j]) | (((uint)(ushort)b[j]) << 16);
      }
    }
    short8_t qf = *(const short8_t*)(qbuf + (size_t)((w0 + r) * qN + qn0 + n) * qstride + qoff + h * 32 + g * 8);
    __syncthreads();

    f32x4 esum = zf, o0 = zf, o1 = zf;

    #pragma unroll
    for (int vp = 0; vp < 6; ++vp) {
      #pragma unroll
      for (int half = 0; half < 2; ++half) {
        int s = 2 * vp + half;
        int v0 = s * 16;
        short8_t kf = *(const short8_t*)&Ks[(v0 + r) * KS_ST + g * 8];
        int base2 = 176 + SGN * (w0 - v0);
        const ushort* krp = KRg + (size_t)(base2 + r) * 256;
        const ushort* qrp = QRg + (size_t)(base2 + r) * 256;
        short8_t krf0 = *(const short8_t*)krp;
        short8_t krf1 = *(const short8_t*)(krp + 16 * 256);
        short8_t qrf0 = *(const short8_t*)qrp;
        short8_t qrf1 = *(const short8_t*)(qrp + 16 * 256);
        __builtin_amdgcn_s_setprio(1);
        f32x4 t1  = MFMA(kf, qf, zf);
        f32x4 t3a = MFMA(kf, qrf0, zf);
        f32x4 t3b = MFMA(kf, qrf1, zf);
        f32x4 t2a = MFMA(qf, krf0, zf);
        f32x4 t2b = MFMA(qf, krf1, zf);
        __builtin_amdgcn_s_setprio(0);
        #pragma unroll
        for (int reg = 0; reg < 4; ++reg) {
          flat[(g4 + reg) * B2_ST + ca] = t2a[reg];
          flat[(g4 + reg) * B2_ST + cbn] = t2b[reg];
        }
        f32x4 p2v = *(const f32x4*)&flat[r * B2_ST + rdcol];
        f32x4 ev;
        #pragma unroll
        for (int reg = 0; reg < 4; ++reg) {
          int js = 15 + SGN * (r - g4 - reg);
          int idx = (lane & 48) | (js & 15);
          float v3a = __shfl(t3a[reg], idx);
          float v3b = __shfl(t3b[reg], idx);
          float p3 = (js < 16) ? v3a : v3b;
          float e = __expf((t1[reg] + p2v[reg] + p3) * SCALE);
          ev[reg] = e;
          esum[reg] += e;
        }
        uint pa = (uint)f2b(ev[0]) | ((uint)f2b(ev[1]) << 16);
        uint pbu = (uint)f2b(ev[2]) | ((uint)f2b(ev[3]) << 16);
        *(uint2*)&PL[r * PL_ST + 8 * half + 2 * g] = make_uint2(pa, pbu);
      }
      union { uint u[4]; short8_t s8; } pb;
      uint4 pr = *(const uint4*)&PL[r * PL_ST + 4 * g];
      pb.u[0] = pr.x; pb.u[1] = pr.y; pb.u[2] = pr.z; pb.u[3] = pr.w;
      short8_t vt0 = *(const short8_t*)&Vt[r * VT_ST + vp * 32 + g * 8];
      short8_t vt1 = *(const short8_t*)&Vt[(16 + r) * VT_ST + vp * 32 + g * 8];
      __builtin_amdgcn_s_setprio(1);
      o0 = MFMA(vt0, pb.s8, o0);
      o1 = MFMA(vt1, pb.s8, o1);
      __builtin_amdgcn_s_setprio(0);
    }

    float ssum = (esum[0] + esum[1]) + (esum[2] + esum[3]);
    ssum += __shfl_xor(ssum, 16);
    ssum += __shfl_xor(ssum, 32);

    float inv = 1.0f / ssum;
    ushort4 u0, u1;
    u0.x = f2b(o0[0] * inv); u0.y = f2b(o0[1] * inv);
    u0.z = f2b(o0[2] * inv); u0.w = f2b(o0[3] * inv);
    u1.x = f2b(o1[0] * inv); u1.y = f2b(o1[1] * inv);
    u1.z = f2b(o1[2] * inv); u1.w = f2b(o1[3] * inv);
    size_t rowb = (size_t)((w0 + r) * oN + n) * CC + h * 32;
    *(ushort4*)(obuf + rowb + g4) = u0;
    *(ushort4*)(obuf + rowb + 16 + g4) = u1;
  }
}

// ---------------------------------------------------------------------------
extern "C" void kernel_launch(void* const* d_in, const int* in_sizes, int n_in,
                              void* d_out, int out_size, void* d_ws, size_t ws_size,
                              hipStream_t stream) {
  const float* feat_left  = (const float*)d_in[0];
  const float* feat_right = (const float*)d_in[1];
  const float* pos_enc    = (const float*)d_in[2];
  const float* s_iw = (const float*)d_in[3];
  const float* s_ib = (const float*)d_in[4];
  const float* s_ow = (const float*)d_in[5];
  const float* s_ob = (const float*)d_in[6];
  const float* s_g  = (const float*)d_in[7];
  const float* s_b  = (const float*)d_in[8];
  const float* c_iw = (const float*)d_in[9];
  const float* c_ib = (const float*)d_in[10];
  const float* c_ow = (const float*)d_in[11];
  const float* c_ob = (const float*)d_in[12];
  const float* c_g1 = (const float*)d_in[13];
  const float* c_b1 = (const float*)d_in[14];
  const float* c_g2 = (const float*)d_in[15];
  const float* c_b2 = (const float*)d_in[16];

  char* W = (char*)d_ws;
  float*  feat    = (float*)W;                       // 25165824 B
  ushort* f2s     = (ushort*)(W + 25165824);         // 12582912 B (s-LN / c1-LN, aliased lifetimes)
  ushort* qkv     = (ushort*)(W + 37748736);         // 37748736 B
  ushort* obuf    = (ushort*)(W + 75497472);         // 12582912 B (attn out; upper half = f2_c2)
  ushort* kv2     = (ushort*)(W + 88080384);         // 12582912 B
  ushort* rrb_all = (ushort*)(W + 100663296);        // 1568768 B
  ushort* wbf     = (ushort*)(W + 102232064);        // 1048576 B

  ushort* f2c1 = f2s;                                 // alias (disjoint lifetime)
  ushort* f2c2 = obuf + WW * HNN * CC;                // obuf upper half, compact HNN layout

  const int GEMM_LDS = 128 * 128 * 2 * 2 + 128 * 4;           // 66048 B
  const int OUT_LDS  = 128 * 128 * 2 * 2 + 128 * 4 + 2048;    // 68096 B
  hipFuncSetAttribute(reinterpret_cast<const void*>(&k_gemm_bf16),
                      hipFuncAttributeMaxDynamicSharedMemorySize, GEMM_LDS);
  hipFuncSetAttribute(reinterpret_cast<const void*>(&k_gemm_out),
                      hipFuncAttributeMaxDynamicSharedMemorySize, OUT_LDS);
  hipFuncSetAttribute(reinterpret_cast<const void*>(&k_rr),
                      hipFuncAttributeMaxDynamicSharedMemorySize, GEMM_LDS);

  k_build_feat<<<dim3(6, 64, 16), 256, 0, stream>>>(feat_left, feat_right, feat);
  k_rr<<<dim3(3, 2, 8), 256, GEMM_LDS, stream>>>(pos_enc, s_iw, s_ib, c_iw, c_ib, rrb_all);
  k_wconv<<<512, 256, 0, stream>>>(s_iw, s_ow, c_iw, c_ow, wbf);

  const ushort* siw_bf_base = wbf;
  const ushort* sow_bf_base = wbf + 196608;
  const ushort* ciw_bf_base = wbf + 262144;
  const ushort* cow_bf_base = wbf + 458752;

  const int T_FULL = WW * NTOT;
  const int T_HALF = WW * HNN;

  // layer-0 input LN
  k_ln<<<T_FULL / 4, 256, 0, stream>>>(feat, f2s, s_g, s_b, 0, NTOT);

  for (int i = 0; i < NLAY; ++i) {
    const float* sib = s_ib + i * 384;
    const float* sob = s_ob + i * CC;
    const float* cib = c_ib + i * 384;
    const float* cob = c_ob + i * CC;
    const ushort* siw_bf = siw_bf_base + (size_t)i * 384 * CC;
    const ushort* sow_bf = sow_bf_base + (size_t)i * CC * CC;
    const ushort* ciw_bf = ciw_bf_base + (size_t)i * 384 * CC;
    const ushort* cow_bf = cow_bf_base + (size_t)i * CC * CC;
    const ushort* rr_self  = rrb_all + (size_t)(2 * i) * 383 * 256;
    const ushort* rr_cross = rrb_all + (size_t)(2 * i + 1) * 383 * 256;
    int last = (i == NLAY - 1);
    float* mir = last ? (float*)d_out : nullptr;
    const float* sg_n = s_g + (i + 1) * CC;   // next-layer s-LN params
    const float* sb_n = s_b + (i + 1) * CC;

    // 1) qkv projection
    k_gemm_bf16<<<dim3(T_FULL / 128, 3), 256, GEMM_LDS, stream>>>(
        f2s, NTOT, 0, siw_bf, sib, qkv, NTOT, 0, 384, T_FULL, NTOT);
    // 2) self attention (NGRP=2: rr L1 reuse)
    k_attn_mfma<-1, 2><<<(NTOT / 2) * NH * 3, 256, 0, stream>>>(
        qkv, 384, 0, NTOT, 0, qkv, 384, 128, 256, NTOT, 0,
        rr_self, obuf, NTOT, NTOT);
    // 3) self out-proj + residual + LN(c_g1) -> f2c1 (full)
    k_gemm_out<<<T_FULL / 128, 256, OUT_LDS, stream>>>(
        obuf, NTOT, sow_bf, sob, feat, 0, nullptr,
        c_g1 + i * CC, c_b1 + i * CC, f2c1, NTOT, 0,
        nullptr, nullptr, nullptr, 0, 0, T_FULL, NTOT);
    // 4) cross projections (all 256 tokens)
    k_gemm_bf16<<<dim3(T_FULL / 128, 3), 256, GEMM_LDS, stream>>>(
        f2c1, NTOT, 0, ciw_bf, cib, qkv, NTOT, 0, 384, T_FULL, NTOT);
    // 5) cross attention 1 (q=right, kv=left, flip)
    k_attn_mfma<+1, 1><<<HNN * NH * 3, 256, 0, stream>>>(
        qkv, 384, 0, NTOT, 128, qkv, 384, 128, 256, NTOT, 0,
        rr_cross, obuf, HNN, HNN);
    // 6) cross1 out-proj (fr) + LN(c_g2)->f2c2 + LN(s_g[i+1])->f2s right
    k_gemm_out<<<T_HALF / 128, 256, OUT_LDS, stream>>>(
        obuf, HNN, cow_bf, cob, feat, 128, mir,
        c_g2 + i * CC, c_b2 + i * CC, f2c2, HNN, 0,
        last ? nullptr : sg_n, sb_n, last ? nullptr : f2s, NTOT, 128,
        T_HALF, HNN);
    // 7) kv2 projection
    k_gemm_bf16<<<dim3(T_HALF / 128, 2), 256, GEMM_LDS, stream>>>(
        f2c2, HNN, 0, ciw_bf + 128 * CC, cib + 128, kv2, HNN, 0, 256, T_HALF, HNN);
    // 8) cross attention 2 (q=left, kv=kv2)
    k_attn_mfma<-1, 1><<<HNN * NH * 3, 256, 0, stream>>>(
        qkv, 384, 0, NTOT, 0, kv2, 256, 0, 128, HNN, 0,
        rr_cross, obuf, HNN, HNN);
    // 9) cross2 out-proj (fl) + LN(s_g[i+1])->f2s left
    k_gemm_out<<<T_HALF / 128, 256, OUT_LDS, stream>>>(
        obuf, HNN, cow_bf, cob, feat, 0, mir,
        last ? nullptr : sg_n, sb_n, last ? nullptr : f2s, NTOT, 0,
        nullptr, nullptr, nullptr, 0, 0, T_HALF, HNN);
  }
}

// Round 11
// 1207.775 us; speedup vs baseline: 1.3325x; 1.3325x over previous
//
#include <hip/hip_runtime.h>
#include <hip/hip_bf16.h>
#include <math.h>

#define WW 192
#define NTOT 256
#define HNN 128
#define CC 128
#define NH 4
#define NLAY 4
#define EPSF 1e-5f
#define SCALE 0.17677669529663687f

typedef __attribute__((ext_vector_type(8))) short short8_t;
typedef __attribute__((ext_vector_type(4))) float f32x4;

#define MFMA(a, b, c) __builtin_amdgcn_mfma_f32_16x16x32_bf16(a, b, c, 0, 0, 0)

__device__ __forceinline__ ushort f2b(float f) {
  union { float f; uint u; } x; x.f = f;
  uint r = x.u + 0x7fffu + ((x.u >> 16) & 1u);
  return (ushort)(r >> 16);
}

// ---------------------------------------------------------------------------
// Build feat (W, 256, 128) f32 from feat_left/right (2, 128, 64, 192).
// ---------------------------------------------------------------------------
__global__ __launch_bounds__(256) void k_build_feat(const float* __restrict__ L,
                                                    const float* __restrict__ R,
                                                    float* __restrict__ feat) {
  __shared__ float tile[32][33];
  int wt = blockIdx.x, h0 = blockIdx.y, z = blockIdx.z;
  int ct = z & 3, b = (z >> 2) & 1, side = z >> 3;
  const float* src = side ? R : L;
  int tx = threadIdx.x & 31, ty = threadIdx.x >> 5;
  const float* sp = src + ((size_t)(b * 128 + ct * 32) * 64 + h0) * 192 + wt * 32;
  #pragma unroll
  for (int yy = 0; yy < 4; ++yy) {
    int c = ty * 4 + yy;
    tile[c][tx] = sp[(size_t)c * 64 * 192 + tx];
  }
  __syncthreads();
  int n = 2 * h0 + b + side * 128;
  #pragma unroll
  for (int yy = 0; yy < 4; ++yy) {
    int w = ty * 4 + yy;
    feat[((size_t)(wt * 32 + w) * 256 + n) * 128 + ct * 32 + tx] = tile[tx][w];
  }
}

// ---------------------------------------------------------------------------
// One-shot weight conversion f32 -> bf16.
// ---------------------------------------------------------------------------
__global__ __launch_bounds__(256) void k_wconv(
    const float* __restrict__ s_iw, const float* __restrict__ s_ow,
    const float* __restrict__ c_iw, const float* __restrict__ c_ow,
    ushort* __restrict__ out) {
  int i4 = (blockIdx.x * 256 + threadIdx.x) * 4;
  const float* src;
  int off;
  if (i4 < 196608) { src = s_iw; off = i4; }
  else if (i4 < 262144) { src = s_ow; off = i4 - 196608; }
  else if (i4 < 458752) { src = c_iw; off = i4 - 262144; }
  else { src = c_ow; off = i4 - 458752; }
  float4 v = *(const float4*)(src + off);
  ushort4 o;
  o.x = f2b(v.x); o.y = f2b(v.y); o.z = f2b(v.z); o.w = f2b(v.w);
  *(ushort4*)(out + i4) = o;
}

// ---------------------------------------------------------------------------
// LayerNorm over C=128, f32 in -> bf16 out (used once for layer-0 input).
// ---------------------------------------------------------------------------
__global__ __launch_bounds__(256) void k_ln(const float* __restrict__ src,
                                            ushort* __restrict__ dst,
                                            const float* __restrict__ g,
                                            const float* __restrict__ b,
                                            int n0, int nsub) {
  int t = blockIdx.x * 4 + (threadIdx.x >> 6);
  int lane = threadIdx.x & 63;
  int w = t / nsub, h = t - w * nsub;
  size_t row = (size_t)(w * NTOT + n0 + h) * CC;
  int c0 = lane * 2;
  float2 x = *(const float2*)(src + row + c0);
  float s = x.x + x.y;
  float s2 = x.x * x.x + x.y * x.y;
  #pragma unroll
  for (int o = 1; o < 64; o <<= 1) {
    s += __shfl_xor(s, o);
    s2 += __shfl_xor(s2, o);
  }
  float m = s * (1.0f / 128.0f);
  float var = s2 * (1.0f / 128.0f) - m * m;
  float inv = rsqrtf(var + EPSF);
  float oa = (x.x - m) * inv * g[c0] + b[c0];
  float ob = (x.y - m) * inv * g[c0 + 1] + b[c0 + 1];
  uint pack = (uint)f2b(oa) | ((uint)f2b(ob) << 16);
  *(uint*)(dst + row + c0) = pack;
}

// ---------------------------------------------------------------------------
// Pure-bf16 MFMA GEMM (projections): Y = X @ Wb^T + bias, bf16 out.
// ---------------------------------------------------------------------------
__global__ __launch_bounds__(256) void k_gemm_bf16(
    const ushort* __restrict__ X, int xN, int x0,
    const ushort* __restrict__ Wb, const float* __restrict__ bias,
    ushort* __restrict__ Y, int yN, int y0, int ystride,
    int T, int nsub) {
  extern __shared__ char smem[];
  ushort* As = (ushort*)smem;
  ushort* Bs = As + 128 * 128;
  float* biasS = (float*)(Bs + 128 * 128);

  int bm = blockIdx.x, bn = blockIdx.y;
  int tid = threadIdx.x;

  {
    int row = tid >> 1;
    int ce0 = (tid & 1) * 64;
    int t = bm * 128 + row;
    int w = t / nsub, h = t - w * nsub;
    const ushort* src = X + (size_t)(w * xN + x0 + h) * CC + ce0;
    #pragma unroll
    for (int i = 0; i < 8; ++i) {
      short8_t v = *(const short8_t*)(src + i * 8);
      int cb = (ce0 + i * 8) * 2;
      *(short8_t*)((char*)As + row * 256 + (cb ^ ((row & 7) << 4))) = v;
    }
    const ushort* wsrc = Wb + (size_t)(bn * 128 + row) * CC + ce0;
    #pragma unroll
    for (int i = 0; i < 8; ++i) {
      short8_t v = *(const short8_t*)(wsrc + i * 8);
      int cb = (ce0 + i * 8) * 2;
      *(short8_t*)((char*)Bs + row * 256 + (cb ^ ((row & 7) << 4))) = v;
    }
    if (tid < 128) biasS[tid] = bias[bn * 128 + tid];
  }
  __syncthreads();

  int lane = tid & 63, wid = tid >> 6;
  int wm = (wid >> 1) * 64, wn = (wid & 1) * 64;
  int r = lane & 15, g = lane >> 4;

  f32x4 acc[4][4] = {};
  #pragma unroll
  for (int kc = 0; kc < 4; ++kc) {
    short8_t af[4], bf[4];
    #pragma unroll
    for (int mt = 0; mt < 4; ++mt) {
      int row = wm + mt * 16 + r;
      af[mt] = *(const short8_t*)((const char*)As + row * 256 + ((kc * 64 + g * 16) ^ ((row & 7) << 4)));
    }
    #pragma unroll
    for (int nt = 0; nt < 4; ++nt) {
      int row = wn + nt * 16 + r;
      bf[nt] = *(const short8_t*)((const char*)Bs + row * 256 + ((kc * 64 + g * 16) ^ ((row & 7) << 4)));
    }
    __builtin_amdgcn_s_setprio(1);
    #pragma unroll
    for (int mt = 0; mt < 4; ++mt)
      #pragma unroll
      for (int nt = 0; nt < 4; ++nt)
        acc[mt][nt] = MFMA(af[mt], bf[nt], acc[mt][nt]);
    __builtin_amdgcn_s_setprio(0);
  }

  #pragma unroll
  for (int mt = 0; mt < 4; ++mt) {
    #pragma unroll
    for (int reg = 0; reg < 4; ++reg) {
      int t = bm * 128 + wm + mt * 16 + g * 4 + reg;
      int w = t / nsub, h = t - w * nsub;
      size_t ybase = (size_t)(w * yN + y0 + h) * ystride + bn * 128;
      #pragma unroll
      for (int nt = 0; nt < 4; ++nt) {
        int nn = wn + nt * 16 + r;
        Y[ybase + nn] = f2b(acc[mt][nt][reg] + biasS[nn]);
      }
    }
  }
}

// ---------------------------------------------------------------------------
// Out-projection GEMM (N=128, bn=0) + f32 residual + up to TWO fused
// LayerNorms of the updated rows (row stats block-local: shfl + 2KB LDS).
// ---------------------------------------------------------------------------
__global__ __launch_bounds__(256) void k_gemm_out(
    const ushort* __restrict__ X, int xN,
    const ushort* __restrict__ Wb, const float* __restrict__ bias,
    float* __restrict__ Y, int y0, float* __restrict__ Ymir,
    const float* __restrict__ g1, const float* __restrict__ b1,
    ushort* __restrict__ dst1, int d1N, int d1n0,
    const float* __restrict__ g2, const float* __restrict__ b2,
    ushort* __restrict__ dst2, int d2N, int d2n0,
    int T, int nsub) {
  extern __shared__ char smem[];
  ushort* As = (ushort*)smem;                 // 32768
  ushort* Bs = As + 128 * 128;                // 32768
  float* biasS = (float*)(Bs + 128 * 128);    // 512
  float* rsum = biasS + 128;                  // 1024 (128 x 2)
  float* rsq  = rsum + 256;                   // 1024

  int bm = blockIdx.x;
  int tid = threadIdx.x;

  {
    int row = tid >> 1;
    int ce0 = (tid & 1) * 64;
    int t = bm * 128 + row;
    int w = t / nsub, h = t - w * nsub;
    const ushort* src = X + (size_t)(w * xN + h) * CC + ce0;
    #pragma unroll
    for (int i = 0; i < 8; ++i) {
      short8_t v = *(const short8_t*)(src + i * 8);
      int cb = (ce0 + i * 8) * 2;
      *(short8_t*)((char*)As + row * 256 + (cb ^ ((row & 7) << 4))) = v;
    }
    const ushort* wsrc = Wb + (size_t)row * CC + ce0;
    #pragma unroll
    for (int i = 0; i < 8; ++i) {
      short8_t v = *(const short8_t*)(wsrc + i * 8);
      int cb = (ce0 + i * 8) * 2;
      *(short8_t*)((char*)Bs + row * 256 + (cb ^ ((row & 7) << 4))) = v;
    }
    if (tid < 128) biasS[tid] = bias[tid];
  }
  __syncthreads();

  int lane = tid & 63, wid = tid >> 6;
  int wm = (wid >> 1) * 64, wn = (wid & 1) * 64;
  int r = lane & 15, g = lane >> 4;
  int g4 = g * 4;

  f32x4 acc[4][4] = {};
  #pragma unroll
  for (int kc = 0; kc < 4; ++kc) {
    short8_t af[4], bf[4];
    #pragma unroll
    for (int mt = 0; mt < 4; ++mt) {
      int row = wm + mt * 16 + r;
      af[mt] = *(const short8_t*)((const char*)As + row * 256 + ((kc * 64 + g * 16) ^ ((row & 7) << 4)));
    }
    #pragma unroll
    for (int nt = 0; nt < 4; ++nt) {
      int row = wn + nt * 16 + r;
      bf[nt] = *(const short8_t*)((const char*)Bs + row * 256 + ((kc * 64 + g * 16) ^ ((row & 7) << 4)));
    }
    __builtin_amdgcn_s_setprio(1);
    #pragma unroll
    for (int mt = 0; mt < 4; ++mt)
      #pragma unroll
      for (int nt = 0; nt < 4; ++nt)
        acc[mt][nt] = MFMA(af[mt], bf[nt], acc[mt][nt]);
    __builtin_amdgcn_s_setprio(0);
  }

  // ---- residual + row stats ----
  float nvv[4][4][4];
  #pragma unroll
  for (int mt = 0; mt < 4; ++mt) {
    #pragma unroll
    for (int reg = 0; reg < 4; ++reg) {
      int rloc = wm + mt * 16 + g4 + reg;
      int t = bm * 128 + rloc;
      int w = t / nsub, h = t - w * nsub;
      size_t ybase = (size_t)(w * NTOT + y0 + h) * CC;
      float s = 0.f, q = 0.f;
      #pragma unroll
      for (int nt = 0; nt < 4; ++nt) {
        int nn = wn + nt * 16 + r;
        float nv = Y[ybase + nn] + acc[mt][nt][reg] + biasS[nn];
        Y[ybase + nn] = nv;
        if (Ymir) Ymir[ybase + nn] = nv;
        nvv[mt][reg][nt] = nv;
        s += nv;
        q += nv * nv;
      }
      #pragma unroll
      for (int o = 1; o < 16; o <<= 1) {
        s += __shfl_xor(s, o);
        q += __shfl_xor(q, o);
      }
      if (r == 0) {
        rsum[rloc * 2 + (wn >> 6)] = s;
        rsq[rloc * 2 + (wn >> 6)] = q;
      }
    }
  }
  if (!dst1) return;
  __syncthreads();

  float g1c[4], b1c[4], g2c[4], b2c[4];
  #pragma unroll
  for (int nt = 0; nt < 4; ++nt) {
    int nn = wn + nt * 16 + r;
    g1c[nt] = g1[nn]; b1c[nt] = b1[nn];
    if (dst2) { g2c[nt] = g2[nn]; b2c[nt] = b2[nn]; }
  }
  #pragma unroll
  for (int mt = 0; mt < 4; ++mt) {
    #pragma unroll
    for (int reg = 0; reg < 4; ++reg) {
      int rloc = wm + mt * 16 + g4 + reg;
      int t = bm * 128 + rloc;
      int w = t / nsub, h = t - w * nsub;
      float S = rsum[rloc * 2] + rsum[rloc * 2 + 1];
      float Q = rsq[rloc * 2] + rsq[rloc * 2 + 1];
      float m = S * (1.0f / 128.0f);
      float inv = rsqrtf(Q * (1.0f / 128.0f) - m * m + EPSF);
      size_t d1base = (size_t)(w * d1N + d1n0 + h) * CC;
      size_t d2base = dst2 ? (size_t)(w * d2N + d2n0 + h) * CC : 0;
      #pragma unroll
      for (int nt = 0; nt < 4; ++nt) {
        int nn = wn + nt * 16 + r;
        float xn = (nvv[mt][reg][nt] - m) * inv;
        dst1[d1base + nn] = f2b(xn * g1c[nt] + b1c[nt]);
        if (dst2) dst2[d2base + nn] = f2b(xn * g2c[nt] + b2c[nt]);
      }
    }
  }
}

// ---------------------------------------------------------------------------
// Batched rr GEMM (once): out_all[z] = pos_enc @ W_z[:256].T + b_z[:256]
// ---------------------------------------------------------------------------
__global__ __launch_bounds__(256) void k_rr(
    const float* __restrict__ pos_enc,
    const float* __restrict__ s_iw, const float* __restrict__ s_ib,
    const float* __restrict__ c_iw, const float* __restrict__ c_ib,
    ushort* __restrict__ out_all) {
  extern __shared__ char smem[];
  ushort* As = (ushort*)smem;
  ushort* Bs = As + 128 * 128;
  float* biasS = (float*)(Bs + 128 * 128);

  int bm = blockIdx.x, bn = blockIdx.y, z = blockIdx.z;
  int layer = z >> 1;
  const float* Wt = ((z & 1) ? c_iw : s_iw) + (size_t)layer * 384 * CC;
  const float* bias = ((z & 1) ? c_ib : s_ib) + layer * 384;
  ushort* out = out_all + (size_t)z * 383 * 256;
  int tid = threadIdx.x;

  {
    int row = tid >> 1;
    int ce0 = (tid & 1) * 64;
    int t = bm * 128 + row;
    bool ok = (t < 383);
    const float* src = pos_enc + (size_t)t * CC + ce0;
    #pragma unroll
    for (int i = 0; i < 8; ++i) {
      float4 v0 = ok ? *(const float4*)(src + i * 8) : make_float4(0.f, 0.f, 0.f, 0.f);
      float4 v1 = ok ? *(const float4*)(src + i * 8 + 4) : make_float4(0.f, 0.f, 0.f, 0.f);
      short8_t pv;
      pv[0] = (short)f2b(v0.x); pv[1] = (short)f2b(v0.y);
      pv[2] = (short)f2b(v0.z); pv[3] = (short)f2b(v0.w);
      pv[4] = (short)f2b(v1.x); pv[5] = (short)f2b(v1.y);
      pv[6] = (short)f2b(v1.z); pv[7] = (short)f2b(v1.w);
      int cb = (ce0 + i * 8) * 2;
      *(short8_t*)((char*)As + row * 256 + (cb ^ ((row & 7) << 4))) = pv;
    }
    const float* wsrc = Wt + (size_t)(bn * 128 + row) * CC + ce0;
    #pragma unroll
    for (int i = 0; i < 8; ++i) {
      float4 v0 = *(const float4*)(wsrc + i * 8);
      float4 v1 = *(const float4*)(wsrc + i * 8 + 4);
      short8_t pv;
      pv[0] = (short)f2b(v0.x); pv[1] = (short)f2b(v0.y);
      pv[2] = (short)f2b(v0.z); pv[3] = (short)f2b(v0.w);
      pv[4] = (short)f2b(v1.x); pv[5] = (short)f2b(v1.y);
      pv[6] = (short)f2b(v1.z); pv[7] = (short)f2b(v1.w);
      int cb = (ce0 + i * 8) * 2;
      *(short8_t*)((char*)Bs + row * 256 + (cb ^ ((row & 7) << 4))) = pv;
    }
    if (tid < 128) biasS[tid] = bias[bn * 128 + tid];
  }
  __syncthreads();

  int lane = tid & 63, wid = tid >> 6;
  int wm = (wid >> 1) * 64, wn = (wid & 1) * 64;
  int r = lane & 15, g = lane >> 4;

  f32x4 acc[4][4] = {};
  #pragma unroll
  for (int kc = 0; kc < 4; ++kc) {
    short8_t af[4], bf[4];
    #pragma unroll
    for (int mt = 0; mt < 4; ++mt) {
      int row = wm + mt * 16 + r;
      af[mt] = *(const short8_t*)((const char*)As + row * 256 + ((kc * 64 + g * 16) ^ ((row & 7) << 4)));
    }
    #pragma unroll
    for (int nt = 0; nt < 4; ++nt) {
      int row = wn + nt * 16 + r;
      bf[nt] = *(const short8_t*)((const char*)Bs + row * 256 + ((kc * 64 + g * 16) ^ ((row & 7) << 4)));
    }
    #pragma unroll
    for (int mt = 0; mt < 4; ++mt)
      #pragma unroll
      for (int nt = 0; nt < 4; ++nt)
        acc[mt][nt] = MFMA(af[mt], bf[nt], acc[mt][nt]);
  }

  #pragma unroll
  for (int mt = 0; mt < 4; ++mt) {
    #pragma unroll
    for (int reg = 0; reg < 4; ++reg) {
      int t = bm * 128 + wm + mt * 16 + g * 4 + reg;
      if (t < 383) {
        #pragma unroll
        for (int nt = 0; nt < 4; ++nt) {
          int nn = wn + nt * 16 + r;
          out[(size_t)t * 256 + bn * 128 + nn] = f2b(acc[mt][nt][reg] + biasS[nn]);
        }
      }
    }
  }
}

// ---------------------------------------------------------------------------
// Fused rel-pos attention — EXACT round-8 body (known-good: 86.5 us,
// no scratch). One (n, head, w-tile) per block; no outer loop wrappers
// (round 6 & 10 both showed wrapper-induced scratch spill).
// ---------------------------------------------------------------------------
#define KS_ST 36
#define VT_ST 196
#define B2_ST 37
#define PL_ST 20

template <int SGN>
__global__ __launch_bounds__(256, 4) void k_attn_mfma(
    const ushort* __restrict__ qbuf, int qstride, int qoff, int qN, int qn0,
    const ushort* __restrict__ kvbuf, int kvstride, int koff, int voff, int kN, int kn0,
    const ushort* __restrict__ rrb,
    ushort* __restrict__ obuf, int oN,
    int nblk) {
  __shared__ ushort Ks[192 * KS_ST];    // 13824 B
  __shared__ ushort Vt[32 * VT_ST];     // 12544 B
  __shared__ float Sb[4 * 16 * B2_ST];  //  9472 B
  __shared__ uint PLb[4 * 16 * PL_ST];  //  5120 B

  int bid = blockIdx.x;
  int n = bid % nblk;
  int rest = bid / nblk;
  int h = rest & 3;
  int ts = rest >> 2;
  int tid = threadIdx.x;
  int lane = tid & 63, wid = tid >> 6;
  int r = lane & 15, g = lane >> 4;
  int g4 = g * 4;

  for (int i = tid; i < 768; i += 256) {
    int row = i >> 2, c8 = (i & 3) * 8;
    *(short8_t*)&Ks[row * KS_ST + c8] =
        *(const short8_t*)(kvbuf + (size_t)(row * kN + kn0 + n) * kvstride + koff + h * 32 + c8);
  }
  {
    uint* Vtu = (uint*)Vt;
    for (int i = tid; i < 384; i += 256) {
      int dg = i / 96;
      int p = i - dg * 96;
      const ushort* vb = kvbuf + (size_t)((2 * p) * kN + kn0 + n) * kvstride + voff + h * 32 + dg * 8;
      short8_t a = *(const short8_t*)vb;
      short8_t b = *(const short8_t*)(vb + (size_t)kN * kvstride);
      #pragma unroll
      for (int j = 0; j < 8; ++j)
        Vtu[(dg * 8 + j) * 98 + p] = ((uint)(ushort)a[j]) | (((uint)(ushort)b[j]) << 16);
    }
  }
  int w0 = (ts * 4 + wid) * 16;
  short8_t qf = *(const short8_t*)(qbuf + (size_t)((w0 + r) * qN + qn0 + n) * qstride + qoff + h * 32 + g * 8);
  __syncthreads();

  float* flat = Sb + wid * 16 * B2_ST;
  uint* PL = PLb + wid * 16 * PL_ST;
  const ushort* KRg = rrb + 128 + h * 32 + g * 8;
  const ushort* QRg = rrb + h * 32 + g * 8;
  const f32x4 zf = {0.f, 0.f, 0.f, 0.f};

  int ca = (SGN < 0) ? (r + 1) : (31 - r);
  int cbn = (SGN < 0) ? (17 + r) : (15 - r);
  int rdcol = 16 - r + g4;

  f32x4 esum = zf, o0 = zf, o1 = zf;

  #pragma unroll
  for (int vp = 0; vp < 6; ++vp) {
    #pragma unroll
    for (int half = 0; half < 2; ++half) {
      int s = 2 * vp + half;
      int v0 = s * 16;
      short8_t kf = *(const short8_t*)&Ks[(v0 + r) * KS_ST + g * 8];
      int base2 = 176 + SGN * (w0 - v0);
      const ushort* krp = KRg + (size_t)(base2 + r) * 256;
      const ushort* qrp = QRg + (size_t)(base2 + r) * 256;
      short8_t krf0 = *(const short8_t*)krp;
      short8_t krf1 = *(const short8_t*)(krp + 16 * 256);
      short8_t qrf0 = *(const short8_t*)qrp;
      short8_t qrf1 = *(const short8_t*)(qrp + 16 * 256);
      __builtin_amdgcn_s_setprio(1);
      f32x4 t1  = MFMA(kf, qf, zf);
      f32x4 t3a = MFMA(kf, qrf0, zf);
      f32x4 t3b = MFMA(kf, qrf1, zf);
      f32x4 t2a = MFMA(qf, krf0, zf);
      f32x4 t2b = MFMA(qf, krf1, zf);
      __builtin_amdgcn_s_setprio(0);
      #pragma unroll
      for (int reg = 0; reg < 4; ++reg) {
        flat[(g4 + reg) * B2_ST + ca] = t2a[reg];
        flat[(g4 + reg) * B2_ST + cbn] = t2b[reg];
      }
      f32x4 p2v = *(const f32x4*)&flat[r * B2_ST + rdcol];
      f32x4 ev;
      #pragma unroll
      for (int reg = 0; reg < 4; ++reg) {
        int js = 15 + SGN * (r - g4 - reg);
        int idx = (lane & 48) | (js & 15);
        float v3a = __shfl(t3a[reg], idx);
        float v3b = __shfl(t3b[reg], idx);
        float p3 = (js < 16) ? v3a : v3b;
        float e = __expf((t1[reg] + p2v[reg] + p3) * SCALE);
        ev[reg] = e;
        esum[reg] += e;
      }
      uint pa = (uint)f2b(ev[0]) | ((uint)f2b(ev[1]) << 16);
      uint pbu = (uint)f2b(ev[2]) | ((uint)f2b(ev[3]) << 16);
      *(uint2*)&PL[r * PL_ST + 8 * half + 2 * g] = make_uint2(pa, pbu);
    }
    union { uint u[4]; short8_t s8; } pb;
    uint4 pr = *(const uint4*)&PL[r * PL_ST + 4 * g];
    pb.u[0] = pr.x; pb.u[1] = pr.y; pb.u[2] = pr.z; pb.u[3] = pr.w;
    short8_t vt0 = *(const short8_t*)&Vt[r * VT_ST + vp * 32 + g * 8];
    short8_t vt1 = *(const short8_t*)&Vt[(16 + r) * VT_ST + vp * 32 + g * 8];
    __builtin_amdgcn_s_setprio(1);
    o0 = MFMA(vt0, pb.s8, o0);
    o1 = MFMA(vt1, pb.s8, o1);
    __builtin_amdgcn_s_setprio(0);
  }

  float ssum = (esum[0] + esum[1]) + (esum[2] + esum[3]);
  ssum += __shfl_xor(ssum, 16);
  ssum += __shfl_xor(ssum, 32);

  float inv = 1.0f / ssum;
  ushort4 u0, u1;
  u0.x = f2b(o0[0] * inv); u0.y = f2b(o0[1] * inv);
  u0.z = f2b(o0[2] * inv); u0.w = f2b(o0[3] * inv);
  u1.x = f2b(o1[0] * inv); u1.y = f2b(o1[1] * inv);
  u1.z = f2b(o1[2] * inv); u1.w = f2b(o1[3] * inv);
  size_t rowb = (size_t)((w0 + r) * oN + n) * CC + h * 32;
  *(ushort4*)(obuf + rowb + g4) = u0;
  *(ushort4*)(obuf + rowb + 16 + g4) = u1;
}

// ---------------------------------------------------------------------------
extern "C" void kernel_launch(void* const* d_in, const int* in_sizes, int n_in,
                              void* d_out, int out_size, void* d_ws, size_t ws_size,
                              hipStream_t stream) {
  const float* feat_left  = (const float*)d_in[0];
  const float* feat_right = (const float*)d_in[1];
  const float* pos_enc    = (const float*)d_in[2];
  const float* s_iw = (const float*)d_in[3];
  const float* s_ib = (const float*)d_in[4];
  const float* s_ow = (const float*)d_in[5];
  const float* s_ob = (const float*)d_in[6];
  const float* s_g  = (const float*)d_in[7];
  const float* s_b  = (const float*)d_in[8];
  const float* c_iw = (const float*)d_in[9];
  const float* c_ib = (const float*)d_in[10];
  const float* c_ow = (const float*)d_in[11];
  const float* c_ob = (const float*)d_in[12];
  const float* c_g1 = (const float*)d_in[13];
  const float* c_b1 = (const float*)d_in[14];
  const float* c_g2 = (const float*)d_in[15];
  const float* c_b2 = (const float*)d_in[16];

  char* W = (char*)d_ws;
  float*  feat    = (float*)W;                       // 25165824 B
  ushort* f2s     = (ushort*)(W + 25165824);         // 12582912 B
  ushort* qkv     = (ushort*)(W + 37748736);         // 37748736 B
  ushort* obuf    = (ushort*)(W + 75497472);         // 12582912 B (attn out; upper half = f2_c2)
  ushort* kv2     = (ushort*)(W + 88080384);         // 12582912 B
  ushort* rrb_all = (ushort*)(W + 100663296);        // 1568768 B
  ushort* wbf     = (ushort*)(W + 102232064);        // 1048576 B

  ushort* f2c1 = f2s;                                 // alias (disjoint lifetime)
  ushort* f2c2 = obuf + WW * HNN * CC;                // obuf upper half, compact HNN layout

  const int GEMM_LDS = 128 * 128 * 2 * 2 + 128 * 4;           // 66048 B
  const int OUT_LDS  = 128 * 128 * 2 * 2 + 128 * 4 + 2048;    // 68096 B
  hipFuncSetAttribute(reinterpret_cast<const void*>(&k_gemm_bf16),
                      hipFuncAttributeMaxDynamicSharedMemorySize, GEMM_LDS);
  hipFuncSetAttribute(reinterpret_cast<const void*>(&k_gemm_out),
                      hipFuncAttributeMaxDynamicSharedMemorySize, OUT_LDS);
  hipFuncSetAttribute(reinterpret_cast<const void*>(&k_rr),
                      hipFuncAttributeMaxDynamicSharedMemorySize, GEMM_LDS);

  k_build_feat<<<dim3(6, 64, 16), 256, 0, stream>>>(feat_left, feat_right, feat);
  k_rr<<<dim3(3, 2, 8), 256, GEMM_LDS, stream>>>(pos_enc, s_iw, s_ib, c_iw, c_ib, rrb_all);
  k_wconv<<<512, 256, 0, stream>>>(s_iw, s_ow, c_iw, c_ow, wbf);

  const ushort* siw_bf_base = wbf;
  const ushort* sow_bf_base = wbf + 196608;
  const ushort* ciw_bf_base = wbf + 262144;
  const ushort* cow_bf_base = wbf + 458752;

  const int T_FULL = WW * NTOT;
  const int T_HALF = WW * HNN;

  // layer-0 input LN
  k_ln<<<T_FULL / 4, 256, 0, stream>>>(feat, f2s, s_g, s_b, 0, NTOT);

  for (int i = 0; i < NLAY; ++i) {
    const float* sib = s_ib + i * 384;
    const float* sob = s_ob + i * CC;
    const float* cib = c_ib + i * 384;
    const float* cob = c_ob + i * CC;
    const ushort* siw_bf = siw_bf_base + (size_t)i * 384 * CC;
    const ushort* sow_bf = sow_bf_base + (size_t)i * CC * CC;
    const ushort* ciw_bf = ciw_bf_base + (size_t)i * 384 * CC;
    const ushort* cow_bf = cow_bf_base + (size_t)i * CC * CC;
    const ushort* rr_self  = rrb_all + (size_t)(2 * i) * 383 * 256;
    const ushort* rr_cross = rrb_all + (size_t)(2 * i + 1) * 383 * 256;
    int last = (i == NLAY - 1);
    float* mir = last ? (float*)d_out : nullptr;
    const float* sg_n = s_g + (i + 1) * CC;
    const float* sb_n = s_b + (i + 1) * CC;

    // 1) qkv projection
    k_gemm_bf16<<<dim3(T_FULL / 128, 3), 256, GEMM_LDS, stream>>>(
        f2s, NTOT, 0, siw_bf, sib, qkv, NTOT, 0, 384, T_FULL, NTOT);
    // 2) self attention
    k_attn_mfma<-1><<<NTOT * NH * 3, 256, 0, stream>>>(
        qkv, 384, 0, NTOT, 0, qkv, 384, 128, 256, NTOT, 0,
        rr_self, obuf, NTOT, NTOT);
    // 3) self out-proj + residual + LN(c_g1) -> f2c1 (full)
    k_gemm_out<<<T_FULL / 128, 256, OUT_LDS, stream>>>(
        obuf, NTOT, sow_bf, sob, feat, 0, nullptr,
        c_g1 + i * CC, c_b1 + i * CC, f2c1, NTOT, 0,
        nullptr, nullptr, nullptr, 0, 0, T_FULL, NTOT);
    // 4) cross projections (all 256 tokens)
    k_gemm_bf16<<<dim3(T_FULL / 128, 3), 256, GEMM_LDS, stream>>>(
        f2c1, NTOT, 0, ciw_bf, cib, qkv, NTOT, 0, 384, T_FULL, NTOT);
    // 5) cross attention 1 (q=right, kv=left, flip)
    k_attn_mfma<+1><<<HNN * NH * 3, 256, 0, stream>>>(
        qkv, 384, 0, NTOT, 128, qkv, 384, 128, 256, NTOT, 0,
        rr_cross, obuf, HNN, HNN);
    // 6) cross1 out-proj (fr) + LN(c_g2)->f2c2 + LN(s_g[i+1])->f2s right
    k_gemm_out<<<T_HALF / 128, 256, OUT_LDS, stream>>>(
        obuf, HNN, cow_bf, cob, feat, 128, mir,
        c_g2 + i * CC, c_b2 + i * CC, f2c2, HNN, 0,
        last ? nullptr : sg_n, sb_n, last ? nullptr : f2s, NTOT, 128,
        T_HALF, HNN);
    // 7) kv2 projection
    k_gemm_bf16<<<dim3(T_HALF / 128, 2), 256, GEMM_LDS, stream>>>(
        f2c2, HNN, 0, ciw_bf + 128 * CC, cib + 128, kv2, HNN, 0, 256, T_HALF, HNN);
    // 8) cross attention 2 (q=left, kv=kv2)
    k_attn_mfma<-1><<<HNN * NH * 3, 256, 0, stream>>>(
        qkv, 384, 0, NTOT, 0, kv2, 256, 0, 128, HNN, 0,
        rr_cross, obuf, HNN, HNN);
    // 9) cross2 out-proj (fl) + LN(s_g[i+1])->f2s left
    k_gemm_out<<<T_HALF / 128, 256, OUT_LDS, stream>>>(
        obuf, HNN, cow_bf, cob, feat, 0, mir,
        last ? nullptr : sg_n, sb_n, last ? nullptr : f2s, NTOT, 0,
        nullptr, nullptr, nullptr, 0, 0, T_HALF, HNN);
  }
}